// Round 13
// baseline (376.978 us; speedup 1.0000x reference)
//
#include <hip/hip_runtime.h>

#define B_TOT 8192
#define T_OBS 128
#define T_FUT 64
#define T_ALL 192
#define DIN 5
#define HD 128
#define BT 16          // batch rows per block (one 16-row tile)
#define LDSTR 136      // LDS row stride in shorts (272 B, 16B-aligned rows)
#define NTHR 256       // 4 waves/block; 512 blocks -> 2 blocks/CU

#define LOG2E 1.44269504088896340736f

typedef __attribute__((ext_vector_type(8))) short short8;
typedef __attribute__((ext_vector_type(4))) float f32x4;
typedef __attribute__((ext_vector_type(2))) unsigned int u32x2;
typedef __attribute__((ext_vector_type(4))) unsigned int u32x4;

__device__ inline short f2bf(float f) {
    unsigned u = __float_as_uint(f);
    u += 0x7FFFu + ((u >> 16) & 1u);   // round-to-nearest-even
    return (short)(u >> 16);
}

// packed f32->bf16 (RNE), lo <- s0, hi <- s1
__device__ inline unsigned cvtpk(float lo, float hi) {
    unsigned r;
    asm volatile("v_cvt_pk_bf16_f32 %0, %1, %2" : "=v"(r) : "v"(lo), "v"(hi));
    return r;
}

__device__ inline f32x4 MFMA(short8 a, short8 b, f32x4 c) {
    return __builtin_amdgcn_mfma_f32_16x16x32_bf16(a, b, c, 0, 0, 0);
}

__device__ inline short8 load_w8s(const float* p, float s) {
    float4 a = *reinterpret_cast<const float4*>(p);
    float4 b = *reinterpret_cast<const float4*>(p + 4);
    short8 r;
    r[0] = f2bf(a.x * s); r[1] = f2bf(a.y * s); r[2] = f2bf(a.z * s); r[3] = f2bf(a.w * s);
    r[4] = f2bf(b.x * s); r[5] = f2bf(b.y * s); r[6] = f2bf(b.z * s); r[7] = f2bf(b.w * s);
    return r;
}
__device__ inline short8 load_w5s(const float* p, float s) {
    short8 r = (short8)0;
    r[0] = f2bf(p[0] * s); r[1] = f2bf(p[1] * s); r[2] = f2bf(p[2] * s);
    r[3] = f2bf(p[3] * s); r[4] = f2bf(p[4] * s);
    return r;
}

// R13: 256 threads = 4 waves, BT=16 -> 512 blocks -> 2 blocks/CU.
// Same 8 waves/CU as R12, but split into TWO INDEPENDENT BARRIER GROUPS:
// when block A's waves drain their per-step barrier, block B's waves (at a
// different phase) keep issuing on the shared SIMD. R12 measured ~60% of
// step time as issue-idle lockstep latency -- this is the lever.
// Register math (why this works where R2/R10 failed): 2x256-thr blocks =
// 2 waves/SIMD -> budget 256 regs/wave (R10's 2x512-thr needed <=128).
// Per-wave: 30 short8 weights (120, two 16-col slices) + ah 16 + biases 32
// + hreg 8 + x5 5 + addr ~20 = ~200 arch + ~16 AGPR < 256. Head weights +
// head bias in LDS (validated R5-R10).
// launch_bounds(256,2): arg2=min blocks/CU (session-deduced semantics)
// -> 8 waves/CU -> 2 waves/SIMD -> 256-reg cap. No >2-waves/SIMD request
// (the 64-VGPR spill wall of R1/R4-R7).
// Wave w owns gate-cols [32w,32w+32) of r/z/n as slices g=0,1; block's 16
// rows are one B-tile shared by both slices -> LDS reads HALVE vs R12
// (4 b128/lane/step). Loop split (R12, validated) retained.
__global__ __launch_bounds__(NTHR, 2)
void gru_tracemodel_kernel(const float* __restrict__ obs, const float* __restrict__ target,
                           const float* __restrict__ eWih, const float* __restrict__ eWhh,
                           const float* __restrict__ ebih, const float* __restrict__ ebhh,
                           const float* __restrict__ cWih, const float* __restrict__ cWhh,
                           const float* __restrict__ cbih, const float* __restrict__ cbhh,
                           const float* __restrict__ headW, const float* __restrict__ headb,
                           float* __restrict__ out)
{
    __shared__ __attribute__((aligned(16))) short Abuf[2][BT][LDSTR];
    __shared__ __attribute__((aligned(16))) short Hw[DIN][LDSTR];   // head W, bf16
    __shared__ float HbLds[8];

    const int tid  = threadIdx.x;
    const int wave = tid >> 6;     // 0..3
    const int lane = tid & 63;
    const int q    = lane >> 4;    // k-group of A/B frags; row-group of C/D
    const int c    = lane & 15;    // non-K index of A/B frags; col of C/D
    const int b0   = blockIdx.x * BT;
    const int wb0  = wave * 32;    // this wave's 32 gate-cols (2 slices)

    // h0 = 0
    for (int i = tid; i < 2 * BT * LDSTR; i += NTHR) ((short*)Abuf)[i] = 0;

    // ---- weight fragments (A-operand: lane holds W'[n][k]) ----
    // [g] = 16-col slice; kt 0..3: Whh K-tiles; kt 4: zero-padded Wih x-tile
    short8 Wr[2][5], Wz[2][5], Wn[2][5];
    f32x4  br4[2], bz4[2], bnh4[2], bni4[2];

    auto load_phase = [&](const float* Wih, const float* Whh,
                          const float* bih, const float* bhh) {
        #pragma unroll
        for (int g = 0; g < 2; ++g) {
            const int nr = 0 * HD + wb0 + 16 * g + c;
            const int nz = 1 * HD + wb0 + 16 * g + c;
            const int nn = 2 * HD + wb0 + 16 * g + c;
            #pragma unroll
            for (int kt = 0; kt < 4; ++kt) {
                Wr[g][kt] = load_w8s(Whh + nr * HD + kt * 32 + q * 8, LOG2E);
                Wz[g][kt] = load_w8s(Whh + nz * HD + kt * 32 + q * 8, LOG2E);
                Wn[g][kt] = load_w8s(Whh + nn * HD + kt * 32 + q * 8, 2.f * LOG2E);
            }
            Wr[g][4] = (q == 0) ? load_w5s(Wih + nr * DIN, LOG2E) : (short8)0;
            Wz[g][4] = (q == 0) ? load_w5s(Wih + nz * DIN, LOG2E) : (short8)0;
            Wn[g][4] = (q == 0) ? load_w5s(Wih + nn * DIN, 2.f * LOG2E) : (short8)0;
            const int n0 = wb0 + 16 * g + q * 4;
            #pragma unroll
            for (int r = 0; r < 4; ++r) {
                br4[g][r]  = (bih[0 * HD + n0 + r] + bhh[0 * HD + n0 + r]) * LOG2E;
                bz4[g][r]  = (bih[1 * HD + n0 + r] + bhh[1 * HD + n0 + r]) * LOG2E;
                bni4[g][r] = bih[2 * HD + n0 + r] * (2.f * LOG2E);
                bnh4[g][r] = bhh[2 * HD + n0 + r] * (2.f * LOG2E);
            }
        }
    };
    load_phase(eWih, eWhh, ebih, ebhh);

    // head weights -> LDS once (wave 0); first read far behind barriers
    if (wave == 0 && c < DIN) {
        #pragma unroll
        for (int kt = 0; kt < 4; ++kt) {
            short8 w = load_w8s(headW + c * HD + kt * 32 + q * 8, 1.f);
            *reinterpret_cast<short8*>(&Hw[c][kt * 32 + q * 8]) = w;
        }
    }
    if (tid < 8) HbLds[tid] = (tid < DIN) ? headb[tid] : 0.f;

    // fp32 carried h: hreg[g][r] = h[batch c][gate-dim wb0+16g+q*4+r]
    float hreg[2][4] = {{0.f,0.f,0.f,0.f},{0.f,0.f,0.f,0.f}};

    const float* obsr = obs    + (size_t)(b0 + c) * (T_OBS * DIN);
    const float* tgtr = target + (size_t)(b0 + c) * (T_FUT * DIN);
    float x5[5] = {0, 0, 0, 0, 0};
    if (q == 0) {
        float4 v4 = *reinterpret_cast<const float4*>(obsr);
        x5[0] = v4.x; x5[1] = v4.y; x5[2] = v4.z; x5[3] = v4.w;
        x5[4] = obsr[4];
    }

// One GRU time step. T runtime; DO_HEAD/ENC are 0/1 literals (dead-folded).
#define GRU_STEP(T, DO_HEAD, ENC)                                              \
  {                                                                            \
    __syncthreads();                                                           \
    const int p_ = (T) & 1;                                                    \
    short8 ah[4];                                                              \
    {                                                                          \
      const short* ap = &Abuf[p_][c][0];                                       \
      _Pragma("unroll")                                                        \
      for (int kt = 0; kt < 4; ++kt)                                           \
        ah[kt] = *reinterpret_cast<const short8*>(ap + kt * 32 + q * 8);       \
    }                                                                          \
    if (DO_HEAD) {                                                             \
      const int s_ = (T) - (T_OBS + 1);                                        \
      if (wave == (s_ & 3)) {                                                  \
        const short* hwp = &Hw[(c < DIN) ? c : 0][0];                          \
        f32x4 acc = {0.f, 0.f, 0.f, 0.f};                                      \
        _Pragma("unroll")                                                      \
        for (int kt = 0; kt < 4; ++kt) {                                       \
          short8 wh = *reinterpret_cast<const short8*>(hwp + kt * 32 + q * 8); \
          acc = MFMA(wh, ah[kt], acc);                                         \
        }                                                                      \
        const int d0 = q * 4;                                                  \
        if (d0 < DIN) {                                                        \
          float* op = out + ((size_t)(b0 + c) * T_FUT + s_) * DIN + d0;        \
          op[0] = acc[0] + HbLds[d0];                                          \
          if (q == 0) {                                                        \
            op[1] = acc[1] + HbLds[1];                                         \
            op[2] = acc[2] + HbLds[2];                                         \
            op[3] = acc[3] + HbLds[3];                                         \
          }                                                                    \
        }                                                                      \
      }                                                                        \
    }                                                                          \
    short8 ax;                                                                 \
    {                                                                          \
      u32x4 va = { cvtpk(x5[0], x5[1]), cvtpk(x5[2], x5[3]),                   \
                   cvtpk(x5[4], 0.f), 0u };                                    \
      ax = __builtin_bit_cast(short8, va);                                     \
      if (q == 0) {                                                            \
        const int tn_ = (T) + 1;                                               \
        const float* px = (ENC)                                                \
            ? (obsr + ((tn_ < T_OBS) ? tn_ : (T_OBS - 1)) * DIN)               \
            : (tgtr + (tn_ - T_OBS - 1) * DIN);                                \
        float4 v4 = *reinterpret_cast<const float4*>(px);                      \
        x5[0] = v4.x; x5[1] = v4.y; x5[2] = v4.z; x5[3] = v4.w;                \
        x5[4] = px[4];                                                         \
      }                                                                        \
    }                                                                          \
    _Pragma("unroll")                                                          \
    for (int g = 0; g < 2; ++g) {                                              \
      f32x4 aR  = MFMA(Wr[g][0], ah[0], br4[g]);                               \
      f32x4 aZ  = MFMA(Wz[g][0], ah[0], bz4[g]);                               \
      f32x4 aNh = MFMA(Wn[g][0], ah[0], bnh4[g]);                              \
      _Pragma("unroll")                                                        \
      for (int kt = 1; kt < 4; ++kt) {                                         \
        aR  = MFMA(Wr[g][kt], ah[kt], aR);                                     \
        aZ  = MFMA(Wz[g][kt], ah[kt], aZ);                                     \
        aNh = MFMA(Wn[g][kt], ah[kt], aNh);                                    \
      }                                                                        \
      aR  = MFMA(Wr[g][4], ax, aR);                                            \
      aZ  = MFMA(Wz[g][4], ax, aZ);                                            \
      f32x4 aNi = MFMA(Wn[g][4], ax, bni4[g]);                                 \
      float hn[4];                                                             \
      _Pragma("unroll")                                                        \
      for (int r = 0; r < 4; ++r) {                                            \
        float er  = __builtin_amdgcn_exp2f(-aR[r]);                            \
        float rv  = __builtin_amdgcn_rcpf(1.f + er);                           \
        float yv  = fmaf(rv, aNh[r], aNi[r]);                                  \
        float ey  = __builtin_amdgcn_exp2f(yv);                                \
        float ez  = __builtin_amdgcn_exp2f(-aZ[r]);                            \
        float d2  = 1.f + ey;                                                  \
        float d1  = 1.f + ez;                                                  \
        float em1 = ey - 1.f;                                                  \
        float num = fmaf(ez, em1, hreg[g][r] * d2);                            \
        float h_  = num * __builtin_amdgcn_rcpf(d1 * d2);                      \
        hreg[g][r] = h_;                                                       \
        hn[r] = h_;                                                            \
      }                                                                        \
      u32x2 wv = { cvtpk(hn[0], hn[1]), cvtpk(hn[2], hn[3]) };                 \
      *reinterpret_cast<u32x2*>(                                               \
          &Abuf[1 - p_][c][wb0 + 16 * g + q * 4]) = wv;                        \
    }                                                                          \
  }

    // encoder: t = 0..127 (no head; x from obs, clamped select for t=127)
    for (int t = 0; t < T_OBS; ++t) GRU_STEP(t, 0, 1);

    // transition: switch to cell weights (register-only; between barriers)
    load_phase(cWih, cWhh, cbih, cbhh);
    GRU_STEP(T_OBS, 0, 0);   // t = 128; prefetch target[0]

    // rollout: t = 129..191 (head fires for s = t-129; guard-free prefetch)
    for (int t = T_OBS + 1; t < T_ALL; ++t) GRU_STEP(t, 1, 0);

    // final: t = 192 -- head only, fired by wave 3 (s = 63)
    __syncthreads();
    if (wave == ((T_FUT - 1) & 3)) {
        const int p_ = T_ALL & 1;
        const int s_ = T_FUT - 1;
        const int d0 = q * 4;
        const short* ap  = &Abuf[p_][c][0];
        const short* hwp = &Hw[(c < DIN) ? c : 0][0];
        f32x4 acc = {0.f, 0.f, 0.f, 0.f};
        #pragma unroll
        for (int kt = 0; kt < 4; ++kt) {
            short8 h8 = *reinterpret_cast<const short8*>(ap + kt * 32 + q * 8);
            short8 wh = *reinterpret_cast<const short8*>(hwp + kt * 32 + q * 8);
            acc = MFMA(wh, h8, acc);
        }
        if (d0 < DIN) {
            float* op = out + ((size_t)(b0 + c) * T_FUT + s_) * DIN + d0;
            op[0] = acc[0] + HbLds[d0];
            if (q == 0) {
                op[1] = acc[1] + HbLds[1];
                op[2] = acc[2] + HbLds[2];
                op[3] = acc[3] + HbLds[3];
            }
        }
    }
#undef GRU_STEP
}

extern "C" void kernel_launch(void* const* d_in, const int* in_sizes, int n_in,
                              void* d_out, int out_size, void* d_ws, size_t ws_size,
                              hipStream_t stream)
{
    (void)in_sizes; (void)n_in; (void)d_ws; (void)ws_size; (void)out_size;
    gru_tracemodel_kernel<<<dim3(B_TOT / BT), dim3(NTHR), 0, stream>>>(
        (const float*)d_in[0],  (const float*)d_in[1],
        (const float*)d_in[2],  (const float*)d_in[3],
        (const float*)d_in[4],  (const float*)d_in[5],
        (const float*)d_in[6],  (const float*)d_in[7],
        (const float*)d_in[8],  (const float*)d_in[9],
        (const float*)d_in[10], (const float*)d_in[11],
        (float*)d_out);
}